// Round 1
// baseline (1554.389 us; speedup 1.0000x reference)
//
#include <hip/hip_runtime.h>
#include <hip/hip_bf16.h>

typedef __attribute__((ext_vector_type(8))) short short8;
typedef __attribute__((ext_vector_type(4))) short short4v;
typedef __attribute__((ext_vector_type(4))) float floatx4;

#define EDIM 256
#define HDIM 512
#define LDIM 16
#define NCOL 2048
#define BM 256      // chains per block
#define KC 32       // k-chunk

__device__ __forceinline__ float fsigmoid(float x){ return 1.0f/(1.0f+__expf(-x)); }
__device__ __forceinline__ float ftanh(float x){ return 2.0f/(1.0f+__expf(-2.0f*x))-1.0f; }
__device__ __forceinline__ float bf2f(short s){
    union { unsigned u; float f; } cv; cv.u = ((unsigned)(unsigned short)s) << 16; return cv.f;
}

__device__ __forceinline__ bool detect_bf16(const short* p) {
    // fp32 buffers' even shorts are low mantissa bits (~uniform) -> exponent
    // field frequently > 0x7B; true bf16 U(-.05,.05) weights never exceed it.
    bool bf = true;
    for (int i = 0; i < 64; i += 2) {
        int e = (((unsigned short)p[i]) >> 7) & 0xFF;
        if (e > 0x7B) bf = false;
    }
    return bf;
}

// ---------------------------------------------------------------------------
// W_hh -> bf16 (copy if already bf16). Also zeroes the 16 group-barrier
// counters used by lstm_fused (workspace is poisoned between runs).
// ---------------------------------------------------------------------------
__global__ void conv_whh(const void* __restrict__ whhp, short* __restrict__ whh_o,
                         unsigned* __restrict__ bar) {
    if (blockIdx.x == 0 && threadIdx.x < 16) bar[threadIdx.x] = 0u;
    bool bf = detect_bf16((const short*)whhp);
    int tid = blockIdx.x * blockDim.x + threadIdx.x;
    int stride = gridDim.x * blockDim.x;
    if (bf) {
        const short* s = (const short*)whhp;
        for (int i = tid; i < NCOL * HDIM; i += stride) whh_o[i] = s[i];
    } else {
        const float* s = (const float*)whhp;
        for (int i = tid; i < NCOL * HDIM; i += stride)
            ((__hip_bfloat16*)whh_o)[i] = __float2bfloat16(s[i]);
    }
}

// ---------------------------------------------------------------------------
// xg[id][j][g] = emb[id] . W_ih[g*512+j] + b_ih + b_hh   (bf16 out)
// Layout is [id][j][4 gates] so the LSTM epilogue gathers one 8B vector.
// ---------------------------------------------------------------------------
__global__ void build_xg(const void* __restrict__ embp, const void* __restrict__ wihp,
                         const void* __restrict__ bihp, const void* __restrict__ bhhp,
                         short* __restrict__ xg)
{
    __shared__ float es[16][EDIM];        // 16 KB
    __shared__ float wsm[32][EDIM + 1];   // 32.1 KB (pad breaks bank conflicts)
    bool bf = detect_bf16((const short*)wihp);
    const int idt = blockIdx.x, ct = blockIdx.y, tt = threadIdx.x;

    if (bf) {
        const __hip_bfloat16* e = (const __hip_bfloat16*)embp;
        const __hip_bfloat16* wv = (const __hip_bfloat16*)wihp;
        for (int p = 0; p < 16; ++p) es[p][tt] = __bfloat162float(e[(idt*16+p)*EDIM + tt]);
        for (int p = 0; p < 32; ++p) wsm[p][tt] = __bfloat162float(wv[(ct*32+p)*EDIM + tt]);
    } else {
        const float* e = (const float*)embp;
        const float* wv = (const float*)wihp;
        for (int p = 0; p < 16; ++p) es[p][tt] = e[(idt*16+p)*EDIM + tt];
        for (int p = 0; p < 32; ++p) wsm[p][tt] = wv[(ct*32+p)*EDIM + tt];
    }
    __syncthreads();

    const int col_l = tt & 31, grp = tt >> 5;   // 8 groups x 2 ids
    const int col = ct * 32 + col_l;            // 0..2047, gate-major
    float bsum = bf ? (__bfloat162float(((const __hip_bfloat16*)bihp)[col]) +
                       __bfloat162float(((const __hip_bfloat16*)bhhp)[col]))
                    : (((const float*)bihp)[col] + ((const float*)bhhp)[col]);
    float a0 = 0.f, a1 = 0.f;
    for (int k = 0; k < EDIM; ++k) {
        float wv = wsm[col_l][k];
        a0 += es[grp*2+0][k] * wv;
        a1 += es[grp*2+1][k] * wv;
    }
    const int jj = col & (HDIM - 1), gsel = col >> 9;
    ((__hip_bfloat16*)xg)[(idt*16 + grp*2 + 0)*NCOL + jj*4 + gsel] = __float2bfloat16(a0 + bsum);
    ((__hip_bfloat16*)xg)[(idt*16 + grp*2 + 1)*NCOL + jj*4 + gsel] = __float2bfloat16(a1 + bsum);
}

// ---------------------------------------------------------------------------
// Fully fused LSTM: all 16 time steps in ONE kernel.
//  - grid 256 blocks (1/CU, guaranteed co-resident), 512 thr = 8 waves.
//  - block (mt, jt): 256 chains x (32 j x 4 gates). W_hh slab persistent in
//    LDS (128 KB, XOR-swizzled). A (h_prev) double-buffered (2x16 KB).
//  - c-state and blended-h in registers across steps; only bf16 h goes to
//    global (ping-pong) for the cross-jt hidden-dim exchange.
//  - sync: per-mt 16-block barrier (device-scope atomics + threadfence);
//    XCD swizzle puts all 16 jt-blocks of an mt on one XCD -> L2-local h.
// ---------------------------------------------------------------------------
__launch_bounds__(512, 2)
__global__ void lstm_fused(const int* __restrict__ seq, const int* __restrict__ lens,
                           const short* __restrict__ whh,   // bf16 [2048][512]
                           const short* __restrict__ xg,    // bf16 [256][512][4]
                           short* __restrict__ hb0, short* __restrict__ hb1,
                           float* __restrict__ out,         // fp32 [4096][512]
                           unsigned* __restrict__ bar)      // [16] counters
{
    __shared__ __align__(16) short Bs[128 * 512];   // 128 KB, swizzled
    __shared__ __align__(16) short As[2][BM * KC];  // 32 KB, swizzled

    const int f  = blockIdx.x;
    // XCD swizzle: blocks round-robin over 8 XCDs by linear id -> choose
    // mt from f%8 so all 16 jt-blocks of an mt land on one XCD (perf only).
    const int mt = ((f & 7) << 1) | ((f >> 3) & 1);
    const int jt = f >> 4;
    const int tid = threadIdx.x;
    const int wave = tid >> 6, lane = tid & 63;
    const int q = lane >> 4, ln = lane & 15;
    const int ms = wave & 3, ns = wave >> 2;
    const int jloc = ns * 16 + ln;        // 0..31 within block's j-slab
    const int jglob = jt * 32 + jloc;

    // ---- stage W_hh slab into LDS once: rows g*32+jl <- whh[g*512+jt*32+jl]
    // swizzle: elem col c stored at c ^ ((row&7)<<3)  (16B-group XOR)
#pragma unroll
    for (int it = 0; it < 16; ++it) {
        int task = it * 512 + tid;            // 8192 tasks of 16 B
        int row = task >> 6, seg = task & 63;
        int grow = (row >> 5) * HDIM + jt * 32 + (row & 31);
        short8 v = *(const short8*)(whh + grow * HDIM + seg * 8);
        *(short8*)&Bs[row * 512 + ((seg * 8) ^ ((row & 7) << 3))] = v;
    }

    const int chainbase = mt * BM + ms * 64 + q * 4;
    const int obase = chainbase * HDIM + jglob;

    int lns_[16];
#pragma unroll
    for (int mf = 0; mf < 4; ++mf)
#pragma unroll
        for (int r = 0; r < 4; ++r)
            lns_[mf * 4 + r] = lens[chainbase + mf * 16 + r];

    float c_st[16], h_st[16];
#pragma unroll
    for (int e = 0; e < 16; ++e) { c_st[e] = 0.f; h_st[e] = 0.f; }

    for (int t = 0; t < LDIM; ++t) {
        const short* hr = (t & 1) ? hb1 : hb0;   // written at step t-1
        short* hw       = (t & 1) ? hb0 : hb1;

        floatx4 acc[4][4];  // [gate][mfrag]
#pragma unroll
        for (int g = 0; g < 4; ++g)
#pragma unroll
            for (int mf = 0; mf < 4; ++mf) acc[g][mf] = (floatx4){0.f, 0.f, 0.f, 0.f};

        if (t > 0) {
            const short* abase = hr + (size_t)mt * BM * HDIM;
            // stage chunk 0 into buffer 0 (A swizzle: c ^ ((row&3)<<3))
#pragma unroll
            for (int p = 0; p < 2; ++p) {
                int task = p * 512 + tid;
                int row = task >> 2, seg = task & 3;
                short8 v = *(const short8*)(abase + row * HDIM + seg * 8);
                *(short8*)&As[0][row * KC + ((seg * 8) ^ ((row & 3) << 3))] = v;
            }
            __syncthreads();
            for (int kc = 0; kc < 16; ++kc) {
                const int b = kc & 1;
                short8 af[4], bfr[4];
#pragma unroll
                for (int mf = 0; mf < 4; ++mf) {
                    int row = ms * 64 + mf * 16 + ln;
                    af[mf] = *(const short8*)&As[b][row * KC + ((q * 8) ^ ((ln & 3) << 3))];
                }
#pragma unroll
                for (int g = 0; g < 4; ++g) {
                    int row = g * 32 + jloc;
                    bfr[g] = *(const short8*)&Bs[row * 512 + ((kc * 32 + q * 8) ^ ((ln & 7) << 3))];
                }
                // issue next-chunk global loads BEFORE the MFMA cluster so
                // HBM/L2 latency hides under compute; ds_write after.
                short8 pv0, pv1; int so0 = 0, so1 = 0;
                if (kc < 15) {
                    int k0 = (kc + 1) * KC;
                    int row0 = tid >> 2, seg0 = tid & 3;
                    pv0 = *(const short8*)(abase + row0 * HDIM + k0 + seg0 * 8);
                    so0 = row0 * KC + ((seg0 * 8) ^ ((row0 & 3) << 3));
                    int row1 = 128 + (tid >> 2);
                    pv1 = *(const short8*)(abase + row1 * HDIM + k0 + seg0 * 8);
                    so1 = row1 * KC + ((seg0 * 8) ^ ((row1 & 3) << 3));
                }
#pragma unroll
                for (int g = 0; g < 4; ++g)
#pragma unroll
                    for (int mf = 0; mf < 4; ++mf)
                        acc[g][mf] = __builtin_amdgcn_mfma_f32_16x16x32_bf16(
                            af[mf], bfr[g], acc[g][mf], 0, 0, 0);
                if (kc < 15) {
                    *(short8*)&As[b ^ 1][so0] = pv0;
                    *(short8*)&As[b ^ 1][so1] = pv1;
                }
                __syncthreads();
            }
        }

        // ---- epilogue: xg gather + cell update. C/D: col=ln, row=q*4+r ----
        int ids[16];
#pragma unroll
        for (int mf = 0; mf < 4; ++mf)
#pragma unroll
            for (int r = 0; r < 4; ++r)
                ids[mf * 4 + r] = seq[(chainbase + mf * 16 + r) * LDIM + t];

        const bool notlast = (t < LDIM - 1);
#pragma unroll
        for (int mf = 0; mf < 4; ++mf)
#pragma unroll
            for (int r = 0; r < 4; ++r) {
                const int e = mf * 4 + r;
                short4v xv = *(const short4v*)(xg + ids[e] * NCOL + jglob * 4);
                float p0 = acc[0][mf][r] + bf2f(xv[0]);
                float p1 = acc[1][mf][r] + bf2f(xv[1]);
                float p2 = acc[2][mf][r] + bf2f(xv[2]);
                float p3 = acc[3][mf][r] + bf2f(xv[3]);
                float ig = fsigmoid(p0);
                float fg = fsigmoid(p1);
                float gg = ftanh(p2);
                float og = fsigmoid(p3);
                float cn = fg * c_st[e] + ig * gg;
                float hn = og * ftanh(cn);
                bool mk = lns_[e] > t;
                float hsv = mk ? hn : h_st[e];
                float csv = mk ? cn : c_st[e];
                h_st[e] = hsv; c_st[e] = csv;
                int off = obase + (mf * 16 + r) * HDIM;
                if (notlast) ((__hip_bfloat16*)hw)[off] = __float2bfloat16(hsv);
                else         out[off] = hsv;   // final h, fp32
            }

        // ---- barrier among the 16 jt-blocks of this mt (the only blocks
        // whose h-writes we read next step). Device-scope fences keep it
        // correct even if the XCD-placement assumption is wrong.
        if (notlast) {
            __threadfence();              // release h-stores (agent scope)
            __syncthreads();
            if (tid == 0) {
                atomicAdd(&bar[mt], 1u);  // device-scope by default
                const unsigned target = 16u * (unsigned)(t + 1);
                while (__hip_atomic_load(&bar[mt], __ATOMIC_ACQUIRE,
                                         __HIP_MEMORY_SCOPE_AGENT) < target)
                    __builtin_amdgcn_s_sleep(2);
            }
            __syncthreads();
            __threadfence();              // acquire: invalidate stale L1/L2
        }
    }
}

extern "C" void kernel_launch(void* const* d_in, const int* in_sizes, int n_in,
                              void* d_out, int out_size, void* d_ws, size_t ws_size,
                              hipStream_t stream) {
    const int* seq  = (const int*)d_in[0];
    const int* lens = (const int*)d_in[1];

    // ws: h_even 4M | h_odd 4M | xg 1M | whh_bf 2M | bar 64B  (<= proven 11.14M)
    char* w = (char*)d_ws;
    short* h_even = (short*)w;
    short* h_odd  = (short*)(w + 4u*1024*1024);
    short* xg     = (short*)(w + 8u*1024*1024);
    short* whh_bf = (short*)(w + 9u*1024*1024);
    unsigned* bar = (unsigned*)(w + 11u*1024*1024);
    float* outp   = (float*)d_out;

    conv_whh<<<512, 256, 0, stream>>>(d_in[4], whh_bf, bar);
    build_xg<<<dim3(16, 64), 256, 0, stream>>>(d_in[2], d_in[3], d_in[5], d_in[6], xg);
    lstm_fused<<<256, 512, 0, stream>>>(seq, lens, whh_bf, xg, h_even, h_odd, outp, bar);
}

// Round 2
// 445.110 us; speedup vs baseline: 3.4921x; 3.4921x over previous
//
#include <hip/hip_runtime.h>
#include <hip/hip_bf16.h>

typedef __attribute__((ext_vector_type(8))) short short8;
typedef __attribute__((ext_vector_type(4))) short short4v;
typedef __attribute__((ext_vector_type(4))) float floatx4;

#define EDIM 256
#define HDIM 512
#define LDIM 16
#define NCOL 2048
#define BM 256      // chains per block
#define KC 32       // k-chunk

__device__ __forceinline__ float fsigmoid(float x){ return 1.0f/(1.0f+__expf(-x)); }
__device__ __forceinline__ float ftanh(float x){ return 2.0f/(1.0f+__expf(-2.0f*x))-1.0f; }
__device__ __forceinline__ float bf2f(short s){
    union { unsigned u; float f; } cv; cv.u = ((unsigned)(unsigned short)s) << 16; return cv.f;
}

__device__ __forceinline__ bool detect_bf16(const short* p) {
    // fp32 buffers' even shorts are low mantissa bits (~uniform) -> exponent
    // field frequently > 0x7B; true bf16 U(-.05,.05) weights never exceed it.
    bool bf = true;
    for (int i = 0; i < 64; i += 2) {
        int e = (((unsigned short)p[i]) >> 7) & 0xFF;
        if (e > 0x7B) bf = false;
    }
    return bf;
}

// ---------------------------------------------------------------------------
// W_hh -> bf16 (copy if already bf16). Also zeroes the group-barrier
// counters used by lstm_fused (workspace is poisoned between runs).
// bar layout: counter for mt at bar[mt*32] (128 B apart, no false sharing).
// ---------------------------------------------------------------------------
__global__ void conv_whh(const void* __restrict__ whhp, short* __restrict__ whh_o,
                         unsigned* __restrict__ bar) {
    if (blockIdx.x == 0)
        for (int i = threadIdx.x; i < 512; i += 256) bar[i] = 0u;
    bool bf = detect_bf16((const short*)whhp);
    int tid = blockIdx.x * blockDim.x + threadIdx.x;
    int stride = gridDim.x * blockDim.x;
    if (bf) {
        const short* s = (const short*)whhp;
        for (int i = tid; i < NCOL * HDIM; i += stride) whh_o[i] = s[i];
    } else {
        const float* s = (const float*)whhp;
        for (int i = tid; i < NCOL * HDIM; i += stride)
            ((__hip_bfloat16*)whh_o)[i] = __float2bfloat16(s[i]);
    }
}

// ---------------------------------------------------------------------------
// xg[id][j][g] = emb[id] . W_ih[g*512+j] + b_ih + b_hh   (bf16 out)
// Layout is [id][j][4 gates] so the LSTM epilogue gathers one 8B vector.
// ---------------------------------------------------------------------------
__global__ void build_xg(const void* __restrict__ embp, const void* __restrict__ wihp,
                         const void* __restrict__ bihp, const void* __restrict__ bhhp,
                         short* __restrict__ xg)
{
    __shared__ float es[16][EDIM];        // 16 KB
    __shared__ float wsm[32][EDIM + 1];   // 32.1 KB (pad breaks bank conflicts)
    bool bf = detect_bf16((const short*)wihp);
    const int idt = blockIdx.x, ct = blockIdx.y, tt = threadIdx.x;

    if (bf) {
        const __hip_bfloat16* e = (const __hip_bfloat16*)embp;
        const __hip_bfloat16* wv = (const __hip_bfloat16*)wihp;
        for (int p = 0; p < 16; ++p) es[p][tt] = __bfloat162float(e[(idt*16+p)*EDIM + tt]);
        for (int p = 0; p < 32; ++p) wsm[p][tt] = __bfloat162float(wv[(ct*32+p)*EDIM + tt]);
    } else {
        const float* e = (const float*)embp;
        const float* wv = (const float*)wihp;
        for (int p = 0; p < 16; ++p) es[p][tt] = e[(idt*16+p)*EDIM + tt];
        for (int p = 0; p < 32; ++p) wsm[p][tt] = wv[(ct*32+p)*EDIM + tt];
    }
    __syncthreads();

    const int col_l = tt & 31, grp = tt >> 5;   // 8 groups x 2 ids
    const int col = ct * 32 + col_l;            // 0..2047, gate-major
    float bsum = bf ? (__bfloat162float(((const __hip_bfloat16*)bihp)[col]) +
                       __bfloat162float(((const __hip_bfloat16*)bhhp)[col]))
                    : (((const float*)bihp)[col] + ((const float*)bhhp)[col]);
    float a0 = 0.f, a1 = 0.f;
    for (int k = 0; k < EDIM; ++k) {
        float wv = wsm[col_l][k];
        a0 += es[grp*2+0][k] * wv;
        a1 += es[grp*2+1][k] * wv;
    }
    const int jj = col & (HDIM - 1), gsel = col >> 9;
    ((__hip_bfloat16*)xg)[(idt*16 + grp*2 + 0)*NCOL + jj*4 + gsel] = __float2bfloat16(a0 + bsum);
    ((__hip_bfloat16*)xg)[(idt*16 + grp*2 + 1)*NCOL + jj*4 + gsel] = __float2bfloat16(a1 + bsum);
}

// ---------------------------------------------------------------------------
// Fully fused LSTM: all 16 time steps in ONE kernel.
//  - grid 256 blocks (1/CU, guaranteed co-resident), 512 thr = 8 waves.
//  - block (mt, jt): 256 chains x (32 j x 4 gates). W_hh slab persistent in
//    LDS (128 KB, XOR-swizzled). A (h_prev) double-buffered (2x16 KB).
//  - c-state and blended-h in registers across steps; only bf16 h goes to
//    global (ping-pong) for the cross-jt hidden-dim exchange.
//  - sync: per-mt 16-block barrier. CRITICAL: polls are RELAXED (no cache
//    maintenance); exactly ONE release (wbl2) at arrival and ONE acquire
//    (inv) after the wait per block per step. Round-1's per-poll ACQUIRE
//    invalidated the XCD L2 every ~130 cycles -> 1493us disaster.
// ---------------------------------------------------------------------------
__launch_bounds__(512, 2)
__global__ void lstm_fused(const int* __restrict__ seq, const int* __restrict__ lens,
                           const short* __restrict__ whh,   // bf16 [2048][512]
                           const short* __restrict__ xg,    // bf16 [256][512][4]
                           short* __restrict__ hb0, short* __restrict__ hb1,
                           float* __restrict__ out,         // fp32 [4096][512]
                           unsigned* __restrict__ bar)      // [16*32] padded counters
{
    __shared__ __align__(16) short Bs[128 * 512];   // 128 KB, swizzled
    __shared__ __align__(16) short As[2][BM * KC];  // 32 KB, swizzled

    const int f  = blockIdx.x;
    // XCD swizzle: blocks round-robin over 8 XCDs by linear id -> choose
    // mt from f%8 so all 16 jt-blocks of an mt land on one XCD (perf only).
    const int mt = ((f & 7) << 1) | ((f >> 3) & 1);
    const int jt = f >> 4;
    const int tid = threadIdx.x;
    const int wave = tid >> 6, lane = tid & 63;
    const int q = lane >> 4, ln = lane & 15;
    const int ms = wave & 3, ns = wave >> 2;
    const int jloc = ns * 16 + ln;        // 0..31 within block's j-slab
    const int jglob = jt * 32 + jloc;

    // ---- stage W_hh slab into LDS once: rows g*32+jl <- whh[g*512+jt*32+jl]
    // swizzle: elem col c stored at c ^ ((row&7)<<3)  (16B-group XOR)
#pragma unroll
    for (int it = 0; it < 16; ++it) {
        int task = it * 512 + tid;            // 8192 tasks of 16 B
        int row = task >> 6, seg = task & 63;
        int grow = (row >> 5) * HDIM + jt * 32 + (row & 31);
        short8 v = *(const short8*)(whh + grow * HDIM + seg * 8);
        *(short8*)&Bs[row * 512 + ((seg * 8) ^ ((row & 7) << 3))] = v;
    }

    const int chainbase = mt * BM + ms * 64 + q * 4;
    const int obase = chainbase * HDIM + jglob;
    unsigned* __restrict__ barp = bar + (mt << 5);

    int lns_[16];
#pragma unroll
    for (int mf = 0; mf < 4; ++mf)
#pragma unroll
        for (int r = 0; r < 4; ++r)
            lns_[mf * 4 + r] = lens[chainbase + mf * 16 + r];

    float c_st[16], h_st[16];
#pragma unroll
    for (int e = 0; e < 16; ++e) { c_st[e] = 0.f; h_st[e] = 0.f; }

    for (int t = 0; t < LDIM; ++t) {
        const short* hr = (t & 1) ? hb1 : hb0;   // written at step t-1
        short* hw       = (t & 1) ? hb0 : hb1;

        // issue seq-id loads EARLY: post-acquire they miss to L3; hide the
        // latency under the GEMM instead of serializing the epilogue.
        int ids[16];
#pragma unroll
        for (int mf = 0; mf < 4; ++mf)
#pragma unroll
            for (int r = 0; r < 4; ++r)
                ids[mf * 4 + r] = seq[(chainbase + mf * 16 + r) * LDIM + t];

        floatx4 acc[4][4];  // [gate][mfrag]
#pragma unroll
        for (int g = 0; g < 4; ++g)
#pragma unroll
            for (int mf = 0; mf < 4; ++mf) acc[g][mf] = (floatx4){0.f, 0.f, 0.f, 0.f};

        if (t > 0) {
            const short* abase = hr + (size_t)mt * BM * HDIM;
            // stage chunk 0 into buffer 0 (A swizzle: c ^ ((row&3)<<3))
#pragma unroll
            for (int p = 0; p < 2; ++p) {
                int task = p * 512 + tid;
                int row = task >> 2, seg = task & 3;
                short8 v = *(const short8*)(abase + row * HDIM + seg * 8);
                *(short8*)&As[0][row * KC + ((seg * 8) ^ ((row & 3) << 3))] = v;
            }
            __syncthreads();
            for (int kc = 0; kc < 16; ++kc) {
                const int b = kc & 1;
                short8 af[4], bfr[4];
#pragma unroll
                for (int mf = 0; mf < 4; ++mf) {
                    int row = ms * 64 + mf * 16 + ln;
                    af[mf] = *(const short8*)&As[b][row * KC + ((q * 8) ^ ((ln & 3) << 3))];
                }
#pragma unroll
                for (int g = 0; g < 4; ++g) {
                    int row = g * 32 + jloc;
                    bfr[g] = *(const short8*)&Bs[row * 512 + ((kc * 32 + q * 8) ^ ((ln & 7) << 3))];
                }
                // issue next-chunk global loads BEFORE the MFMA cluster so
                // L2/L3 latency hides under compute; ds_write after.
                short8 pv0, pv1; int so0 = 0, so1 = 0;
                if (kc < 15) {
                    int k0 = (kc + 1) * KC;
                    int row0 = tid >> 2, seg0 = tid & 3;
                    pv0 = *(const short8*)(abase + row0 * HDIM + k0 + seg0 * 8);
                    so0 = row0 * KC + ((seg0 * 8) ^ ((row0 & 3) << 3));
                    int row1 = 128 + (tid >> 2);
                    pv1 = *(const short8*)(abase + row1 * HDIM + k0 + seg0 * 8);
                    so1 = row1 * KC + ((seg0 * 8) ^ ((row1 & 3) << 3));
                }
#pragma unroll
                for (int g = 0; g < 4; ++g)
#pragma unroll
                    for (int mf = 0; mf < 4; ++mf)
                        acc[g][mf] = __builtin_amdgcn_mfma_f32_16x16x32_bf16(
                            af[mf], bfr[g], acc[g][mf], 0, 0, 0);
                if (kc < 15) {
                    *(short8*)&As[b ^ 1][so0] = pv0;
                    *(short8*)&As[b ^ 1][so1] = pv1;
                }
                __syncthreads();
            }
        }

        // ---- epilogue: xg gather + cell update. C/D: col=ln, row=q*4+r ----
        const bool notlast = (t < LDIM - 1);
#pragma unroll
        for (int mf = 0; mf < 4; ++mf)
#pragma unroll
            for (int r = 0; r < 4; ++r) {
                const int e = mf * 4 + r;
                short4v xv = *(const short4v*)(xg + ids[e] * NCOL + jglob * 4);
                float p0 = acc[0][mf][r] + bf2f(xv[0]);
                float p1 = acc[1][mf][r] + bf2f(xv[1]);
                float p2 = acc[2][mf][r] + bf2f(xv[2]);
                float p3 = acc[3][mf][r] + bf2f(xv[3]);
                float ig = fsigmoid(p0);
                float fg = fsigmoid(p1);
                float gg = ftanh(p2);
                float og = fsigmoid(p3);
                float cn = fg * c_st[e] + ig * gg;
                float hn = og * ftanh(cn);
                bool mk = lns_[e] > t;
                float hsv = mk ? hn : h_st[e];
                float csv = mk ? cn : c_st[e];
                h_st[e] = hsv; c_st[e] = csv;
                int off = obase + (mf * 16 + r) * HDIM;
                if (notlast) ((__hip_bfloat16*)hw)[off] = __float2bfloat16(hsv);
                else         out[off] = hsv;   // final h, fp32
            }

        // ---- barrier among the 16 jt-blocks of this mt. One release (L2
        // writeback) at arrival, relaxed polls (NO cache ops), one acquire
        // (L2 invalidate) on exit. __syncthreads drains all waves' vmcnt
        // first, so every h-store is in L2 before the release writeback.
        if (notlast) {
            __syncthreads();
            if (tid == 0) {
                __hip_atomic_fetch_add(barp, 1u, __ATOMIC_RELEASE,
                                       __HIP_MEMORY_SCOPE_AGENT);
                const unsigned target = 16u * (unsigned)(t + 1);
                while (__hip_atomic_load(barp, __ATOMIC_RELAXED,
                                         __HIP_MEMORY_SCOPE_AGENT) < target)
                    __builtin_amdgcn_s_sleep(2);
                __builtin_amdgcn_fence(__ATOMIC_ACQUIRE, "agent");
            }
            __syncthreads();
        }
    }
}

extern "C" void kernel_launch(void* const* d_in, const int* in_sizes, int n_in,
                              void* d_out, int out_size, void* d_ws, size_t ws_size,
                              hipStream_t stream) {
    const int* seq  = (const int*)d_in[0];
    const int* lens = (const int*)d_in[1];

    // ws: h_even 4M | h_odd 4M | xg 1M | whh_bf 2M | bar 2KB (<= proven 11.14M)
    char* w = (char*)d_ws;
    short* h_even = (short*)w;
    short* h_odd  = (short*)(w + 4u*1024*1024);
    short* xg     = (short*)(w + 8u*1024*1024);
    short* whh_bf = (short*)(w + 9u*1024*1024);
    unsigned* bar = (unsigned*)(w + 11u*1024*1024);
    float* outp   = (float*)d_out;

    conv_whh<<<512, 256, 0, stream>>>(d_in[4], whh_bf, bar);
    build_xg<<<dim3(16, 64), 256, 0, stream>>>(d_in[2], d_in[3], d_in[5], d_in[6], xg);
    lstm_fused<<<256, 512, 0, stream>>>(seq, lens, whh_bf, xg, h_even, h_odd, outp, bar);
}